// Round 1
// baseline (703.436 us; speedup 1.0000x reference)
//
#include <hip/hip_runtime.h>
#include <hip/hip_bf16.h>
#include <math.h>

// Problem constants (from reference)
#define B_    2
#define S_    2048
#define DIM_  2048
#define H_    16
#define NOPE_ 128
#define ROPE_ 64
#define VDIM_ 128
#define QR_   1024
#define KVR_  512
#define TOK_  (B_ * S_)   // 4096 token rows

typedef __attribute__((ext_vector_type(8))) short short8;   // 8 bf16 (4 VGPRs)
typedef __attribute__((ext_vector_type(4))) float f32x4;    // MFMA acc

// fp32 -> bf16 (round-to-nearest-even), raw ushort
__device__ __forceinline__ unsigned short f2bf(float f) {
  union { float f; unsigned u; } v; v.f = f;
  unsigned r = v.u + 0x7fffu + ((v.u >> 16) & 1u);
  return (unsigned short)(r >> 16);
}
__device__ __forceinline__ unsigned pk2(float lo, float hi) {
  return (unsigned)f2bf(lo) | ((unsigned)f2bf(hi) << 16);
}

// async global->LDS, 16 B per lane; dest = wave-uniform base + lane*16.
__device__ __forceinline__ void gl_lds16(const unsigned short* g, unsigned short* lds_base) {
  __builtin_amdgcn_global_load_lds(
      (const __attribute__((address_space(1))) void*)g,
      (__attribute__((address_space(3))) void*)lds_base,
      16, 0, 0);
}

__device__ __forceinline__ void store_out(float* p, float v) { *p = v; }
__device__ __forceinline__ void store_out(unsigned short* p, float v) { *p = f2bf(v); }

// ---------------------------------------------------------------------------
// fp32 -> bf16 bulk cast. n8 = elements/8.
// ---------------------------------------------------------------------------
__global__ __launch_bounds__(256) void cvt_bf16(const float* __restrict__ in,
                                                unsigned short* __restrict__ o, int n8) {
  const int idx = blockIdx.x * 256 + threadIdx.x;
  if (idx >= n8) return;
  float4 f0 = *(const float4*)(in + (size_t)idx * 8);
  float4 f1 = *(const float4*)(in + (size_t)idx * 8 + 4);
  uint4 u;
  u.x = pk2(f0.x, f0.y); u.y = pk2(f0.z, f0.w);
  u.z = pk2(f1.x, f1.y); u.w = pk2(f1.z, f1.w);
  *(uint4*)&o[(size_t)idx * 8] = u;
}

// ---------------------------------------------------------------------------
// MFMA GEMM: C[M x N] = A[M x K] @ B[N x K]^T. bf16 in, OutT out.
// Tile 128 x (NT*32), BK=32, 256 threads = 4 waves; wave does 64 x (NT*16).
// ---------------------------------------------------------------------------
template <typename OutT, int NT>
__global__ __launch_bounds__(256) void gemm_bf16(const unsigned short* __restrict__ A,
                                                 const unsigned short* __restrict__ Bm,
                                                 OutT* __restrict__ C,
                                                 int M, int N, int K) {
  constexpr int BN = NT * 32;
  __shared__ unsigned short As[128 * 32];
  __shared__ unsigned short Bs[BN * 32];
  const int tid  = threadIdx.x;
  const int wave = tid >> 6;
  const int lane = tid & 63;
  const int quad = lane >> 4;
  const int l15  = lane & 15;
  const int m0 = blockIdx.y * 128;
  const int n0 = blockIdx.x * BN;
  const int wm = (wave & 1) * 64;
  const int wn = (wave >> 1) * (NT * 16);

  f32x4 acc[4][NT];
#pragma unroll
  for (int i = 0; i < 4; ++i)
#pragma unroll
    for (int j = 0; j < NT; ++j) {
      f32x4 z = {0.f, 0.f, 0.f, 0.f};
      acc[i][j] = z;
    }

  for (int k0 = 0; k0 < K; k0 += 32) {
    __syncthreads();
    // A: 512 chunk-slots, 2/thread
#pragma unroll
    for (int i = 0; i < 2; ++i) {
      const int s = i * 256 + tid;
      const int srow = s >> 2;
      const int sq = (s & 3) ^ ((srow >> 1) & 3);
      gl_lds16(A + (size_t)(m0 + srow) * K + k0 + sq * 8, &As[(i * 256 + wave * 64) * 8]);
    }
    // B: BN*4 chunk-slots
#pragma unroll
    for (int i = 0; i < BN / 64; ++i) {
      const int s = i * 256 + tid;
      const int srow = s >> 2;
      const int sq = (s & 3) ^ ((srow >> 1) & 3);
      const int rb = min(n0 + srow, N - 1);
      gl_lds16(Bm + (size_t)rb * K + k0 + sq * 8, &Bs[(i * 256 + wave * 64) * 8]);
    }
    __syncthreads();

    short8 a[4], b[NT];
#pragma unroll
    for (int i = 0; i < 4; ++i) {
      const int r = wm + i * 16 + l15;
      a[i] = *(const short8*)&As[(r * 4 + (quad ^ ((r >> 1) & 3))) * 8];
    }
#pragma unroll
    for (int j = 0; j < NT; ++j) {
      const int r = wn + j * 16 + l15;
      b[j] = *(const short8*)&Bs[(r * 4 + (quad ^ ((r >> 1) & 3))) * 8];
    }
#pragma unroll
    for (int i = 0; i < 4; ++i)
#pragma unroll
      for (int j = 0; j < NT; ++j)
        acc[i][j] = __builtin_amdgcn_mfma_f32_16x16x32_bf16(a[i], b[j], acc[i][j], 0, 0, 0);
  }

#pragma unroll
  for (int i = 0; i < 4; ++i) {
#pragma unroll
    for (int j = 0; j < NT; ++j) {
      const int col = n0 + wn + j * 16 + l15;
      if (col < N) {
#pragma unroll
        for (int r = 0; r < 4; ++r) {
          const int row = m0 + wm + i * 16 + quad * 4 + r;
          store_out(&C[(size_t)row * N + col], acc[i][j][r]);
        }
      }
    }
  }
}

// ---------------------------------------------------------------------------
// RMSNorm: fp32 in -> bf16 out
// ---------------------------------------------------------------------------
__global__ __launch_bounds__(256) void rmsnorm_bf16(const float* __restrict__ x,
                                                    const float* __restrict__ w,
                                                    unsigned short* __restrict__ o, int n) {
  __shared__ float red[256];
  const int row = blockIdx.x;
  const float* p = x + (size_t)row * n;
  float s = 0.f;
  for (int i = threadIdx.x; i < n; i += 256) { float v = p[i]; s += v * v; }
  red[threadIdx.x] = s;
  __syncthreads();
  for (int off = 128; off > 0; off >>= 1) {
    if (threadIdx.x < off) red[threadIdx.x] += red[threadIdx.x + off];
    __syncthreads();
  }
  const float inv = rsqrtf(red[0] / (float)n + 1e-6f);
  unsigned short* po = o + (size_t)row * n;
  for (int i = threadIdx.x; i < n; i += 256) po[i] = f2bf(p[i] * inv * w[i]);
}

// ---------------------------------------------------------------------------
// Interleaved RoPE: fp32 in -> bf16 out. Layout (rows, heads*64); pos = row % S.
// ---------------------------------------------------------------------------
__global__ void rope_bf16(const float* __restrict__ xin, unsigned short* __restrict__ xout,
                          int heads, int total_pairs) {
  int idx = blockIdx.x * blockDim.x + threadIdx.x;
  if (idx >= total_pairs) return;
  const int i = idx & 31;
  const int h = (idx >> 5) % heads;
  const int row = idx / (32 * heads);
  const int pos = row & (S_ - 1);
  const float freq = expf(-9.210340371976184f * (float)i / 32.0f);
  const float ang = (float)pos * freq;
  const float c = cosf(ang), sn = sinf(ang);
  const float* p = xin + ((size_t)row * heads + h) * 64 + 2 * i;
  unsigned short* q = xout + ((size_t)row * heads + h) * 64 + 2 * i;
  const float x1 = p[0], x2 = p[1];
  q[0] = f2bf(x1 * c - x2 * sn);
  q[1] = f2bf(x1 * sn + x2 * c);
}

// ---------------------------------------------------------------------------
// One-shot V transpose: kv_up V-part [tok][h*256+128..256) -> vt_g[b][h][feat][key]
// ---------------------------------------------------------------------------
__global__ __launch_bounds__(256) void transpose_v(const unsigned short* __restrict__ kv_up,
                                                   unsigned short* __restrict__ vt_g) {
  __shared__ unsigned short T[128 * 72];
  const int tid = threadIdx.x;
  const int k0 = blockIdx.x * 64;
  const int h = blockIdx.y, b = blockIdx.z;
  const size_t tok0 = (size_t)b * S_;
#pragma unroll
  for (int i = 0; i < 2; ++i) {
    const int u = i * 256 + tid;           // 512 units: key-pair kp, 8-feat group c8
    const int kp = u >> 4, c8 = u & 15;
    const unsigned short* p0 =
        kv_up + (tok0 + k0 + 2 * kp) * (size_t)(H_ * 256) + h * 256 + NOPE_ + c8 * 8;
    union { uint4 v; unsigned short s[8]; } r0, r1;
    r0.v = *(const uint4*)p0;
    r1.v = *(const uint4*)(p0 + H_ * 256);
#pragma unroll
    for (int j = 0; j < 8; ++j)
      *(unsigned*)&T[(c8 * 8 + j) * 72 + 2 * kp] = (unsigned)r0.s[j] | ((unsigned)r1.s[j] << 16);
  }
  __syncthreads();
#pragma unroll
  for (int i = 0; i < 4; ++i) {
    const int sl = i * 256 + tid;          // 1024 out-chunks
    const int f = sl >> 3, c = sl & 7;
    *(uint4*)(vt_g + ((size_t)(b * H_ + h) * 128 + f) * S_ + k0 + c * 8) =
        *(const uint4*)&T[f * 72 + c * 8];
  }
}

// ---------------------------------------------------------------------------
// MFMA flash attention, merged-consecutive-pair schedule.
// Block p processes q-tiles {2p, 2p+1} SIMULTANEOUSLY in one K-loop: the two
// strips share every staged K/V tile (their causal prefixes are nested, the
// shorter strip just skips the final K-tile). Stage-iterations per (b,h):
// 528 (two-phase schedule) -> 272 (-48%); MFMA per staged tile doubles, so
// the staging latency that dominated (MfmaUtil 7.9%) is amortized 2x.
// Compute per block is 4p+3 units (imbalanced), so heavy blocks dispatch
// first via pair = 15 - blockIdx.x; longest block < mean CU load.
// Softmax runs in exp2 domain (log2e folded into scale) -> bare v_exp_f32.
// All staging via global_load_lds w16, XOR-swizzled sources; V comes
// pre-transposed from vt_g. 2 __syncthreads per staged tile; Ps round-trip is
// wave-private (same-wave DS ordering + wave_barrier, no block barrier).
// attn_o aliases q_nope: all q_nope reads precede all attn_o writes in-block;
// cross-block regions are (row,head)-disjoint.
// ---------------------------------------------------------------------------
#define LV 72    // Ps stride (64 + 8 pad)

__global__ __launch_bounds__(256) void flash_attn_mfma(const unsigned short* q_nope,
                                                       const unsigned short* __restrict__ q_pe,
                                                       const unsigned short* __restrict__ kv_up,
                                                       const unsigned short* __restrict__ k_rope,
                                                       const unsigned short* __restrict__ vt_g,
                                                       unsigned short* attn_o) {
  __shared__ unsigned short Ksn[64 * 16 * 8];  // 16 KB keys x 128 nope-feats (swizzled)
  __shared__ unsigned short Ksr[64 * 8 * 8];   //  8 KB keys x 64 rope-feats (swizzled)
  __shared__ unsigned short Vt[128 * 8 * 8];   // 16 KB feats x 64 keys (swizzled)
  __shared__ unsigned short Ps[64 * LV];       //  9 KB

  const int tid  = threadIdx.x;
  const int wave = tid >> 6;
  const int lane = tid & 63;
  const int quad = lane >> 4;
  const int l15  = lane & 15;
  const int pair = 15 - blockIdx.x;  // heavy blocks (large qt) dispatch first
  const int h  = blockIdx.y;
  const int b  = blockIdx.z;
  const size_t tok0 = (size_t)b * S_;
  const int qtA = 2 * pair + 1;      // longer strip (owns the last K-tile)
  const int qtB = 2 * pair;          // shorter strip (skips only kt == qtA)
  // 1/sqrt(192) * log2(e): softmax in exp2 domain
  const float scale2 = 0.07216878364870323f * 1.4426950408889634f;

  // Q fragments for both strips (A-layout): row = q0 + wave*16 + l15
  short8 qf[2][6];
#pragma unroll
  for (int st = 0; st < 2; ++st) {
    const int q0 = (st ? qtB : qtA) * 64;
    const size_t qrow = tok0 + q0 + wave * 16 + l15;
    const unsigned short* pn = q_nope + qrow * (size_t)(H_ * NOPE_) + h * NOPE_;
    const unsigned short* pp = q_pe + qrow * (size_t)(H_ * ROPE_) + h * ROPE_;
#pragma unroll
    for (int s = 0; s < 4; ++s) qf[st][s] = *(const short8*)(pn + s * 32 + quad * 8);
#pragma unroll
    for (int s = 4; s < 6; ++s) qf[st][s] = *(const short8*)(pp + (s - 4) * 32 + quad * 8);
  }

  float m_st[2][4], l_st[2][4];
  f32x4 o[2][8];
#pragma unroll
  for (int st = 0; st < 2; ++st) {
#pragma unroll
    for (int r = 0; r < 4; ++r) { m_st[st][r] = -1e30f; l_st[st][r] = 0.f; }
#pragma unroll
    for (int nt = 0; nt < 8; ++nt) { f32x4 z = {0.f, 0.f, 0.f, 0.f}; o[st][nt] = z; }
  }

  for (int kt = 0; kt <= qtA; ++kt) {
    const int k0 = kt * 64;
    __syncthreads();  // prior tile's LDS reads complete before restage

    // --- stage K-nope: 1024 chunk-slots; slot = key*16 + (c ^ (key&15)) ---
#pragma unroll
    for (int i = 0; i < 4; ++i) {
      const int sl = i * 256 + tid;
      const int key = sl >> 4;
      const int c = (sl & 15) ^ (key & 15);
      gl_lds16(kv_up + (tok0 + k0 + key) * (size_t)(H_ * 256) + h * 256 + c * 8,
               &Ksn[(i * 256 + wave * 64) * 8]);
    }
    // --- stage K-rope: 512 slots; slot = key*8 + (c ^ (key&7)) ---
#pragma unroll
    for (int i = 0; i < 2; ++i) {
      const int sl = i * 256 + tid;
      const int key = sl >> 3;
      const int c = (sl & 7) ^ (key & 7);
      gl_lds16(k_rope + (tok0 + k0 + key) * (size_t)ROPE_ + c * 8,
               &Ksr[(i * 256 + wave * 64) * 8]);
    }
    // --- stage V^T: 1024 slots; slot = f*8 + (c ^ (f&7)) ---
#pragma unroll
    for (int i = 0; i < 4; ++i) {
      const int sl = i * 256 + tid;
      const int f = sl >> 3;
      const int c = (sl & 7) ^ (f & 7);
      gl_lds16(vt_g + ((size_t)(b * H_ + h) * 128 + f) * S_ + k0 + c * 8,
               &Vt[(i * 256 + wave * 64) * 8]);
    }
    __syncthreads();  // compiler drains vmcnt before barrier

#pragma unroll
    for (int st = 0; st < 2; ++st) {
      if (st == 1 && kt > qtB) continue;  // strip B skips only the final K-tile
      const int qt = st ? qtB : qtA;

      // --- S = Q K^T (wave strip 16 x 64) ---
      f32x4 sacc[4];
#pragma unroll
      for (int nt = 0; nt < 4; ++nt) { f32x4 z = {0.f, 0.f, 0.f, 0.f}; sacc[nt] = z; }
#pragma unroll
      for (int s = 0; s < 4; ++s) {
#pragma unroll
        for (int nt = 0; nt < 4; ++nt) {
          const int key = nt * 16 + l15;
          short8 kb = *(const short8*)&Ksn[(key * 16 + ((s * 4 + quad) ^ (key & 15))) * 8];
          sacc[nt] = __builtin_amdgcn_mfma_f32_16x16x32_bf16(qf[st][s], kb, sacc[nt], 0, 0, 0);
        }
      }
#pragma unroll
      for (int s = 4; s < 6; ++s) {
#pragma unroll
        for (int nt = 0; nt < 4; ++nt) {
          const int key = nt * 16 + l15;
          short8 kb = *(const short8*)&Ksr[(key * 8 + (((s - 4) * 4 + quad) ^ (key & 7))) * 8];
          sacc[nt] = __builtin_amdgcn_mfma_f32_16x16x32_bf16(qf[st][s], kb, sacc[nt], 0, 0, 0);
        }
      }

      float sc[4][4];
#pragma unroll
      for (int nt = 0; nt < 4; ++nt)
#pragma unroll
        for (int r = 0; r < 4; ++r) {
          float v = sacc[nt][r] * scale2;
          if (kt == qt && (nt * 16 + l15) > (wave * 16 + quad * 4 + r)) v = -1e30f;
          sc[nt][r] = v;
        }

      float mt[4];
#pragma unroll
      for (int r = 0; r < 4; ++r)
        mt[r] = fmaxf(fmaxf(sc[0][r], sc[1][r]), fmaxf(sc[2][r], sc[3][r]));
#pragma unroll
      for (int mask = 1; mask <= 8; mask <<= 1)
#pragma unroll
        for (int r = 0; r < 4; ++r) mt[r] = fmaxf(mt[r], __shfl_xor(mt[r], mask, 64));

      float al[4], rs[4];
#pragma unroll
      for (int r = 0; r < 4; ++r) {
        const float mn = fmaxf(m_st[st][r], mt[r]);
        al[r] = exp2f(m_st[st][r] - mn);
        m_st[st][r] = mn;
        rs[r] = 0.f;
      }
#pragma unroll
      for (int nt = 0; nt < 4; ++nt)
#pragma unroll
        for (int r = 0; r < 4; ++r) {
          const float p = exp2f(sc[nt][r] - m_st[st][r]);
          sc[nt][r] = p;
          rs[r] += p;
        }
#pragma unroll
      for (int mask = 1; mask <= 8; mask <<= 1)
#pragma unroll
        for (int r = 0; r < 4; ++r) rs[r] += __shfl_xor(rs[r], mask, 64);
#pragma unroll
      for (int r = 0; r < 4; ++r) l_st[st][r] = l_st[st][r] * al[r] + rs[r];

      // --- P transpose via LDS (wave-private rows; no block barrier needed) ---
#pragma unroll
      for (int nt = 0; nt < 4; ++nt)
#pragma unroll
        for (int r = 0; r < 4; ++r)
          Ps[(wave * 16 + quad * 4 + r) * LV + nt * 16 + l15] = f2bf(sc[nt][r]);
      __builtin_amdgcn_wave_barrier();  // pin order; same-wave DS ops complete in order

      // --- O = O*alpha + P V ---
#pragma unroll
      for (int nt = 0; nt < 8; ++nt)
#pragma unroll
        for (int r = 0; r < 4; ++r) o[st][nt][r] *= al[r];
#pragma unroll
      for (int s = 0; s < 2; ++s) {
        short8 pa = *(const short8*)&Ps[(wave * 16 + l15) * LV + s * 32 + quad * 8];
#pragma unroll
        for (int nt = 0; nt < 8; ++nt) {
          const int f = nt * 16 + l15;
          short8 vb = *(const short8*)&Vt[(f * 8 + ((s * 4 + quad) ^ (f & 7))) * 8];
          o[st][nt] = __builtin_amdgcn_mfma_f32_16x16x32_bf16(pa, vb, o[st][nt], 0, 0, 0);
        }
      }
      __builtin_amdgcn_wave_barrier();  // WAR: Ps reused by the other strip
    }
  }

#pragma unroll
  for (int st = 0; st < 2; ++st) {
    const int q0 = (st ? qtB : qtA) * 64;
    float invl[4];
#pragma unroll
    for (int r = 0; r < 4; ++r) invl[r] = 1.f / l_st[st][r];
#pragma unroll
    for (int nt = 0; nt < 8; ++nt)
#pragma unroll
      for (int r = 0; r < 4; ++r) {
        const size_t row = tok0 + q0 + wave * 16 + quad * 4 + r;
        attn_o[row * (size_t)(H_ * VDIM_) + h * VDIM_ + nt * 16 + l15] =
            f2bf(o[st][nt][r] * invl[r]);
      }
  }
}

// ---------------------------------------------------------------------------
// Launch
// ---------------------------------------------------------------------------
extern "C" void kernel_launch(void* const* d_in, const int* in_sizes, int n_in,
                              void* d_out, int out_size, void* d_ws, size_t ws_size,
                              hipStream_t stream) {
  (void)in_sizes; (void)n_in;
  const float* x         = (const float*)d_in[0];
  const float* wq_down   = (const float*)d_in[1];
  const float* q_norm_w  = (const float*)d_in[2];
  const float* wq_up     = (const float*)d_in[3];
  const float* wq_rope   = (const float*)d_in[4];
  const float* wkv_down  = (const float*)d_in[5];
  const float* kv_norm_w = (const float*)d_in[6];
  const float* wkv_up    = (const float*)d_in[7];
  const float* wk_rope   = (const float*)d_in[8];
  const float* wo        = (const float*)d_in[9];
  float* out = (float*)d_out;

  // ---- workspace carve (identical layout to the passing run)
  const size_t SZ_XBF   = (size_t)TOK_ * DIM_ * 2;
  const size_t SZ_WQD   = (size_t)QR_ * DIM_ * 2;
  const size_t SZ_WKVD  = (size_t)KVR_ * DIM_ * 2;
  const size_t SZ_WKR   = (size_t)ROPE_ * DIM_ * 2;
  const size_t SZ_WQU   = (size_t)H_ * NOPE_ * QR_ * 2;
  const size_t SZ_WQR   = (size_t)H_ * ROPE_ * QR_ * 2;
  const size_t SZ_WKVU  = (size_t)H_ * (NOPE_ + VDIM_) * KVR_ * 2;
  const size_t SZ_WO    = (size_t)DIM_ * H_ * VDIM_ * 2;
  const size_t SZ_QC    = (size_t)TOK_ * QR_ * 4;   // aliases: q_pe fp32, then vt_g
  const size_t SZ_KVC   = (size_t)TOK_ * KVR_ * 4;
  const size_t SZ_QCN   = (size_t)TOK_ * QR_ * 2;
  const size_t SZ_KVCN  = (size_t)TOK_ * KVR_ * 2;
  const size_t SZ_QNOPE = (size_t)TOK_ * H_ * NOPE_ * 2; // aliases attn_o bf16
  const size_t SZ_QPEB  = (size_t)TOK_ * H_ * ROPE_ * 2;
  const size_t SZ_KRF   = (size_t)TOK_ * ROPE_ * 4;
  const size_t SZ_KRB   = (size_t)TOK_ * ROPE_ * 2;
  const size_t SZ_KVUP  = (size_t)TOK_ * H_ * (NOPE_ + VDIM_) * 2;
  const size_t NEED = SZ_XBF + SZ_WQD + SZ_WKVD + SZ_WKR + SZ_WQU + SZ_WQR + SZ_WKVU +
                      SZ_WO + SZ_QC + SZ_KVC + SZ_QCN + SZ_KVCN + SZ_QNOPE + SZ_QPEB +
                      SZ_KRF + SZ_KRB + SZ_KVUP;
  if (ws_size < NEED) {
    hipMemsetAsync(d_out, 0, (size_t)out_size * sizeof(float), stream);
    return;
  }
  char* p = (char*)d_ws;
  unsigned short* x_bf    = (unsigned short*)p; p += SZ_XBF;
  unsigned short* wqd_bf  = (unsigned short*)p; p += SZ_WQD;
  unsigned short* wkvd_bf = (unsigned short*)p; p += SZ_WKVD;
  unsigned short* wkr_bf  = (unsigned short*)p; p += SZ_WKR;
  unsigned short* wqu_bf  = (unsigned short*)p; p += SZ_WQU;
  unsigned short* wqr_bf  = (unsigned short*)p; p += SZ_WQR;
  unsigned short* wkvu_bf = (unsigned short*)p; p += SZ_WKVU;
  unsigned short* wo_bf   = (unsigned short*)p; p += SZ_WO;
  float*          q_c     = (float*)p;          p += SZ_QC;
  float*          kv_c    = (float*)p;          p += SZ_KVC;
  unsigned short* q_cn    = (unsigned short*)p; p += SZ_QCN;
  unsigned short* kv_cn   = (unsigned short*)p; p += SZ_KVCN;
  unsigned short* q_nope  = (unsigned short*)p; p += SZ_QNOPE;
  unsigned short* q_pe_bf = (unsigned short*)p; p += SZ_QPEB;
  float*          k_ropef = (float*)p;          p += SZ_KRF;
  unsigned short* k_ropeb = (unsigned short*)p; p += SZ_KRB;
  unsigned short* kv_upbf = (unsigned short*)p; p += SZ_KVUP;
  float*          q_pe_f  = q_c;                   // q_c dead after rmsnorm
  unsigned short* vt_g    = (unsigned short*)q_c;  // q_pe_f dead after rope_q
  unsigned short* attn_o  = q_nope;                // q_nope dead after flash

  const dim3 blk(256);
  // ---- one-time bf16 casts
  cvt_bf16<<<(TOK_ * DIM_ / 8 + 255) / 256, blk, 0, stream>>>(x, x_bf, TOK_ * DIM_ / 8);
  cvt_bf16<<<(QR_ * DIM_ / 8 + 255) / 256, blk, 0, stream>>>(wq_down, wqd_bf, QR_ * DIM_ / 8);
  cvt_bf16<<<(KVR_ * DIM_ / 8 + 255) / 256, blk, 0, stream>>>(wkv_down, wkvd_bf, KVR_ * DIM_ / 8);
  cvt_bf16<<<(ROPE_ * DIM_ / 8 + 255) / 256, blk, 0, stream>>>(wk_rope, wkr_bf, ROPE_ * DIM_ / 8);
  cvt_bf16<<<(H_ * NOPE_ * QR_ / 8 + 255) / 256, blk, 0, stream>>>(wq_up, wqu_bf, H_ * NOPE_ * QR_ / 8);
  cvt_bf16<<<(H_ * ROPE_ * QR_ / 8 + 255) / 256, blk, 0, stream>>>(wq_rope, wqr_bf, H_ * ROPE_ * QR_ / 8);
  cvt_bf16<<<(H_ * (NOPE_ + VDIM_) * KVR_ / 8 + 255) / 256, blk, 0, stream>>>(wkv_up, wkvu_bf,
                                                                              H_ * (NOPE_ + VDIM_) * KVR_ / 8);
  cvt_bf16<<<(DIM_ * H_ * VDIM_ / 8 + 255) / 256, blk, 0, stream>>>(wo, wo_bf, DIM_ * H_ * VDIM_ / 8);

  // ---- down projections
  gemm_bf16<float, 4><<<dim3(QR_ / 128, TOK_ / 128), blk, 0, stream>>>(x_bf, wqd_bf, q_c, TOK_, QR_, DIM_);
  gemm_bf16<float, 2><<<dim3(KVR_ / 64, TOK_ / 128), blk, 0, stream>>>(x_bf, wkvd_bf, kv_c, TOK_, KVR_, DIM_);
  gemm_bf16<float, 2><<<dim3(1, TOK_ / 128), blk, 0, stream>>>(x_bf, wkr_bf, k_ropef, TOK_, ROPE_, DIM_);

  // ---- RMSNorms
  rmsnorm_bf16<<<TOK_, blk, 0, stream>>>(q_c, q_norm_w, q_cn, QR_);
  rmsnorm_bf16<<<TOK_, blk, 0, stream>>>(kv_c, kv_norm_w, kv_cn, KVR_);

  // ---- up projections
  gemm_bf16<unsigned short, 4><<<dim3(H_ * NOPE_ / 128, TOK_ / 128), blk, 0, stream>>>(
      q_cn, wqu_bf, q_nope, TOK_, H_ * NOPE_, QR_);
  gemm_bf16<float, 4><<<dim3(H_ * ROPE_ / 128, TOK_ / 128), blk, 0, stream>>>(
      q_cn, wqr_bf, q_pe_f, TOK_, H_ * ROPE_, QR_);
  gemm_bf16<unsigned short, 4><<<dim3(H_ * (NOPE_ + VDIM_) / 128, TOK_ / 128), blk, 0, stream>>>(
      kv_cn, wkvu_bf, kv_upbf, TOK_, H_ * (NOPE_ + VDIM_), KVR_);

  // ---- RoPE (q first: frees q_c region for vt_g)
  {
    const int pairs_q = TOK_ * H_ * 32;
    rope_bf16<<<(pairs_q + 255) / 256, blk, 0, stream>>>(q_pe_f, q_pe_bf, H_, pairs_q);
    const int pairs_k = TOK_ * 32;
    rope_bf16<<<(pairs_k + 255) / 256, blk, 0, stream>>>(k_ropef, k_ropeb, 1, pairs_k);
  }

  // ---- V transpose (after rope_q; vt_g aliases q_c region)
  transpose_v<<<dim3(S_ / 64, H_, B_), blk, 0, stream>>>(kv_upbf, vt_g);

  // ---- attention (merged consecutive pairs: grid.x = 16, heavy-first)
  flash_attn_mfma<<<dim3(16, H_, B_), blk, 0, stream>>>(q_nope, q_pe_bf, kv_upbf, k_ropeb, vt_g, attn_o);

  // ---- output projection
  gemm_bf16<float, 4><<<dim3(DIM_ / 128, TOK_ / 128), blk, 0, stream>>>(attn_o, wo_bf, out, TOK_, DIM_, H_ * VDIM_);
}

// Round 2
// 616.867 us; speedup vs baseline: 1.1403x; 1.1403x over previous
//
#include <hip/hip_runtime.h>
#include <hip/hip_bf16.h>
#include <math.h>

// Problem constants (from reference)
#define B_    2
#define S_    2048
#define DIM_  2048
#define H_    16
#define NOPE_ 128
#define ROPE_ 64
#define VDIM_ 128
#define QR_   1024
#define KVR_  512
#define TOK_  (B_ * S_)   // 4096 token rows

typedef __attribute__((ext_vector_type(8))) short short8;   // 8 bf16 (4 VGPRs)
typedef __attribute__((ext_vector_type(4))) float f32x4;    // MFMA acc

// fp32 -> bf16 (round-to-nearest-even), raw ushort
__device__ __forceinline__ unsigned short f2bf(float f) {
  union { float f; unsigned u; } v; v.f = f;
  unsigned r = v.u + 0x7fffu + ((v.u >> 16) & 1u);
  return (unsigned short)(r >> 16);
}
__device__ __forceinline__ unsigned pk2(float lo, float hi) {
  return (unsigned)f2bf(lo) | ((unsigned)f2bf(hi) << 16);
}

// async global->LDS, 16 B per lane; dest = wave-uniform base + lane*16.
__device__ __forceinline__ void gl_lds16(const unsigned short* g, unsigned short* lds_base) {
  __builtin_amdgcn_global_load_lds(
      (const __attribute__((address_space(1))) void*)g,
      (__attribute__((address_space(3))) void*)lds_base,
      16, 0, 0);
}

__device__ __forceinline__ void store_out(float* p, float v) { *p = v; }
__device__ __forceinline__ void store_out(unsigned short* p, float v) { *p = f2bf(v); }

// ---------------------------------------------------------------------------
// fp32 -> bf16 bulk cast. n8 = elements/8.
// ---------------------------------------------------------------------------
__global__ __launch_bounds__(256) void cvt_bf16(const float* __restrict__ in,
                                                unsigned short* __restrict__ o, int n8) {
  const int idx = blockIdx.x * 256 + threadIdx.x;
  if (idx >= n8) return;
  float4 f0 = *(const float4*)(in + (size_t)idx * 8);
  float4 f1 = *(const float4*)(in + (size_t)idx * 8 + 4);
  uint4 u;
  u.x = pk2(f0.x, f0.y); u.y = pk2(f0.z, f0.w);
  u.z = pk2(f1.x, f1.y); u.w = pk2(f1.z, f1.w);
  *(uint4*)&o[(size_t)idx * 8] = u;
}

// ---------------------------------------------------------------------------
// MFMA GEMM: C[M x N] = A[M x K] @ B[N x K]^T. bf16 in, OutT out.
// Tile 128 x (NT*32), BK=32, 256 threads = 4 waves; wave does 64 x (NT*16).
// ---------------------------------------------------------------------------
template <typename OutT, int NT>
__global__ __launch_bounds__(256) void gemm_bf16(const unsigned short* __restrict__ A,
                                                 const unsigned short* __restrict__ Bm,
                                                 OutT* __restrict__ C,
                                                 int M, int N, int K) {
  constexpr int BN = NT * 32;
  __shared__ unsigned short As[128 * 32];
  __shared__ unsigned short Bs[BN * 32];
  const int tid  = threadIdx.x;
  const int wave = tid >> 6;
  const int lane = tid & 63;
  const int quad = lane >> 4;
  const int l15  = lane & 15;
  const int m0 = blockIdx.y * 128;
  const int n0 = blockIdx.x * BN;
  const int wm = (wave & 1) * 64;
  const int wn = (wave >> 1) * (NT * 16);

  f32x4 acc[4][NT];
#pragma unroll
  for (int i = 0; i < 4; ++i)
#pragma unroll
    for (int j = 0; j < NT; ++j) {
      f32x4 z = {0.f, 0.f, 0.f, 0.f};
      acc[i][j] = z;
    }

  for (int k0 = 0; k0 < K; k0 += 32) {
    __syncthreads();
    // A: 512 chunk-slots, 2/thread
#pragma unroll
    for (int i = 0; i < 2; ++i) {
      const int s = i * 256 + tid;
      const int srow = s >> 2;
      const int sq = (s & 3) ^ ((srow >> 1) & 3);
      gl_lds16(A + (size_t)(m0 + srow) * K + k0 + sq * 8, &As[(i * 256 + wave * 64) * 8]);
    }
    // B: BN*4 chunk-slots
#pragma unroll
    for (int i = 0; i < BN / 64; ++i) {
      const int s = i * 256 + tid;
      const int srow = s >> 2;
      const int sq = (s & 3) ^ ((srow >> 1) & 3);
      const int rb = min(n0 + srow, N - 1);
      gl_lds16(Bm + (size_t)rb * K + k0 + sq * 8, &Bs[(i * 256 + wave * 64) * 8]);
    }
    __syncthreads();

    short8 a[4], b[NT];
#pragma unroll
    for (int i = 0; i < 4; ++i) {
      const int r = wm + i * 16 + l15;
      a[i] = *(const short8*)&As[(r * 4 + (quad ^ ((r >> 1) & 3))) * 8];
    }
#pragma unroll
    for (int j = 0; j < NT; ++j) {
      const int r = wn + j * 16 + l15;
      b[j] = *(const short8*)&Bs[(r * 4 + (quad ^ ((r >> 1) & 3))) * 8];
    }
#pragma unroll
    for (int i = 0; i < 4; ++i)
#pragma unroll
      for (int j = 0; j < NT; ++j)
        acc[i][j] = __builtin_amdgcn_mfma_f32_16x16x32_bf16(a[i], b[j], acc[i][j], 0, 0, 0);
  }

#pragma unroll
  for (int i = 0; i < 4; ++i) {
#pragma unroll
    for (int j = 0; j < NT; ++j) {
      const int col = n0 + wn + j * 16 + l15;
      if (col < N) {
#pragma unroll
        for (int r = 0; r < 4; ++r) {
          const int row = m0 + wm + i * 16 + quad * 4 + r;
          store_out(&C[(size_t)row * N + col], acc[i][j][r]);
        }
      }
    }
  }
}

// ---------------------------------------------------------------------------
// RMSNorm: fp32 in -> bf16 out
// ---------------------------------------------------------------------------
__global__ __launch_bounds__(256) void rmsnorm_bf16(const float* __restrict__ x,
                                                    const float* __restrict__ w,
                                                    unsigned short* __restrict__ o, int n) {
  __shared__ float red[256];
  const int row = blockIdx.x;
  const float* p = x + (size_t)row * n;
  float s = 0.f;
  for (int i = threadIdx.x; i < n; i += 256) { float v = p[i]; s += v * v; }
  red[threadIdx.x] = s;
  __syncthreads();
  for (int off = 128; off > 0; off >>= 1) {
    if (threadIdx.x < off) red[threadIdx.x] += red[threadIdx.x + off];
    __syncthreads();
  }
  const float inv = rsqrtf(red[0] / (float)n + 1e-6f);
  unsigned short* po = o + (size_t)row * n;
  for (int i = threadIdx.x; i < n; i += 256) po[i] = f2bf(p[i] * inv * w[i]);
}

// ---------------------------------------------------------------------------
// Interleaved RoPE: fp32 in -> bf16 out. Layout (rows, heads*64); pos = row % S.
// ---------------------------------------------------------------------------
__global__ void rope_bf16(const float* __restrict__ xin, unsigned short* __restrict__ xout,
                          int heads, int total_pairs) {
  int idx = blockIdx.x * blockDim.x + threadIdx.x;
  if (idx >= total_pairs) return;
  const int i = idx & 31;
  const int h = (idx >> 5) % heads;
  const int row = idx / (32 * heads);
  const int pos = row & (S_ - 1);
  const float freq = expf(-9.210340371976184f * (float)i / 32.0f);
  const float ang = (float)pos * freq;
  const float c = cosf(ang), sn = sinf(ang);
  const float* p = xin + ((size_t)row * heads + h) * 64 + 2 * i;
  unsigned short* q = xout + ((size_t)row * heads + h) * 64 + 2 * i;
  const float x1 = p[0], x2 = p[1];
  q[0] = f2bf(x1 * c - x2 * sn);
  q[1] = f2bf(x1 * sn + x2 * c);
}

// ---------------------------------------------------------------------------
// One-shot V transpose: kv_up V-part [tok][h*256+128..256) -> vt_g[b][h][feat][key]
// ---------------------------------------------------------------------------
__global__ __launch_bounds__(256) void transpose_v(const unsigned short* __restrict__ kv_up,
                                                   unsigned short* __restrict__ vt_g) {
  __shared__ unsigned short T[128 * 72];
  const int tid = threadIdx.x;
  const int k0 = blockIdx.x * 64;
  const int h = blockIdx.y, b = blockIdx.z;
  const size_t tok0 = (size_t)b * S_;
#pragma unroll
  for (int i = 0; i < 2; ++i) {
    const int u = i * 256 + tid;           // 512 units: key-pair kp, 8-feat group c8
    const int kp = u >> 4, c8 = u & 15;
    const unsigned short* p0 =
        kv_up + (tok0 + k0 + 2 * kp) * (size_t)(H_ * 256) + h * 256 + NOPE_ + c8 * 8;
    union { uint4 v; unsigned short s[8]; } r0, r1;
    r0.v = *(const uint4*)p0;
    r1.v = *(const uint4*)(p0 + H_ * 256);
#pragma unroll
    for (int j = 0; j < 8; ++j)
      *(unsigned*)&T[(c8 * 8 + j) * 72 + 2 * kp] = (unsigned)r0.s[j] | ((unsigned)r1.s[j] << 16);
  }
  __syncthreads();
#pragma unroll
  for (int i = 0; i < 4; ++i) {
    const int sl = i * 256 + tid;          // 1024 out-chunks
    const int f = sl >> 3, c = sl & 7;
    *(uint4*)(vt_g + ((size_t)(b * H_ + h) * 128 + f) * S_ + k0 + c * 8) =
        *(const uint4*)&T[f * 72 + c * 8];
  }
}

// ---------------------------------------------------------------------------
// MFMA flash attention, balanced schedule + DOUBLE-BUFFERED staging.
// Block = pair i: q-tiles {31-i, i} processed sequentially (33 K-tile
// iterations for every block -> perfect balance, the proven schedule), but
// the two phases are flattened into ONE 33-iteration pipeline:
//   top of iter:  raw s_barrier (WAR: everyone done reading buf[nxt])
//                 issue 10 global_load_lds for tile it+1 -> buf[nxt]
//                 s_waitcnt vmcnt(10) (my tile-it loads landed)
//                 raw s_barrier (ALL tile-it loads landed)
//                 compute tile it on buf[cur]
// Stage latency (the dominant cost: HBM 12%, MfmaUtil 8% at R0) now hides
// under the previous tile's QK^T+softmax+PV instead of serializing with it.
// Raw __builtin_amdgcn_s_barrier (NOT __syncthreads) keeps the prefetch
// loads in flight across the barrier; counted vmcnt never drains to 0 in
// the main loop (T3/T4). LDS = 2x40KB buffers + Ps = 89KB -> 1 block/CU
// (which is all we were getting at 49KB anyway, per OccupancyPercent=11.5).
// Single softmax state; strip-A epilogue + Q reload at the phase boundary
// (no runtime-indexed register arrays -> no scratch). attn_o aliases
// q_nope: both strips' Q rows are read before any attn_o write that could
// touch them (strip-B Q rows are disjoint from strip-A's epilogue rows;
// cross-block regions are (row,head)-disjoint).
// ---------------------------------------------------------------------------
#define LV 72    // Ps stride (64 + 8 pad)

__global__ __launch_bounds__(256) void flash_attn_mfma(const unsigned short* q_nope,
                                                       const unsigned short* __restrict__ q_pe,
                                                       const unsigned short* __restrict__ kv_up,
                                                       const unsigned short* __restrict__ k_rope,
                                                       const unsigned short* __restrict__ vt_g,
                                                       unsigned short* attn_o) {
  __shared__ unsigned short Ksn[2][64 * 16 * 8];  // 2 x 16 KB keys x 128 nope-feats
  __shared__ unsigned short Ksr[2][64 * 8 * 8];   // 2 x  8 KB keys x 64 rope-feats
  __shared__ unsigned short Vt[2][128 * 8 * 8];   // 2 x 16 KB feats x 64 keys
  __shared__ unsigned short Ps[64 * LV];          //      9 KB

  const int tid  = threadIdx.x;
  const int wave = tid >> 6;
  const int lane = tid & 63;
  const int quad = lane >> 4;
  const int l15  = lane & 15;
  const int pair = blockIdx.x;   // 0..15
  const int h  = blockIdx.y;
  const int b  = blockIdx.z;
  const size_t tok0 = (size_t)b * S_;
  // 1/sqrt(192) * log2(e): softmax in exp2 domain
  const float scale2 = 0.07216878364870323f * 1.4426950408889634f;
  const int qtA = 31 - pair;     // phase-0 strip
  const int qtB = pair;          // phase-1 strip
  const int n0  = qtA + 1;       // iterations in phase 0; total always 33

  auto LOADQ = [&](short8* qf, int qt) {
    const size_t qrow = tok0 + qt * 64 + wave * 16 + l15;
    const unsigned short* pn = q_nope + qrow * (size_t)(H_ * NOPE_) + h * NOPE_;
    const unsigned short* pp = q_pe + qrow * (size_t)(H_ * ROPE_) + h * ROPE_;
#pragma unroll
    for (int s = 0; s < 4; ++s) qf[s] = *(const short8*)(pn + s * 32 + quad * 8);
#pragma unroll
    for (int s = 4; s < 6; ++s) qf[s] = *(const short8*)(pp + (s - 4) * 32 + quad * 8);
  };

  // 10 global_load_lds per thread (per wave): Ksn 4 + Ksr 2 + Vt 4.
  auto STAGE = [&](int bi, int kt) {
    const int k0 = kt * 64;
#pragma unroll
    for (int i = 0; i < 4; ++i) {
      const int sl = i * 256 + tid;
      const int key = sl >> 4;
      const int c = (sl & 15) ^ (key & 15);
      gl_lds16(kv_up + (tok0 + k0 + key) * (size_t)(H_ * 256) + h * 256 + c * 8,
               &Ksn[bi][(i * 256 + wave * 64) * 8]);
    }
#pragma unroll
    for (int i = 0; i < 2; ++i) {
      const int sl = i * 256 + tid;
      const int key = sl >> 3;
      const int c = (sl & 7) ^ (key & 7);
      gl_lds16(k_rope + (tok0 + k0 + key) * (size_t)ROPE_ + c * 8,
               &Ksr[bi][(i * 256 + wave * 64) * 8]);
    }
#pragma unroll
    for (int i = 0; i < 4; ++i) {
      const int sl = i * 256 + tid;
      const int f = sl >> 3;
      const int c = (sl & 7) ^ (f & 7);
      gl_lds16(vt_g + ((size_t)(b * H_ + h) * 128 + f) * S_ + k0 + c * 8,
               &Vt[bi][(i * 256 + wave * 64) * 8]);
    }
  };

  short8 qf[6];
  LOADQ(qf, qtA);

  float m_st[4], l_st[4];
  f32x4 o[8];
#pragma unroll
  for (int r = 0; r < 4; ++r) { m_st[r] = -1e30f; l_st[r] = 0.f; }
#pragma unroll
  for (int nt = 0; nt < 8; ++nt) { f32x4 z = {0.f, 0.f, 0.f, 0.f}; o[nt] = z; }

  auto EPI = [&](int qt) {
    float invl[4];
#pragma unroll
    for (int r = 0; r < 4; ++r) invl[r] = 1.f / l_st[r];
#pragma unroll
    for (int nt = 0; nt < 8; ++nt)
#pragma unroll
      for (int r = 0; r < 4; ++r) {
        const size_t row = tok0 + qt * 64 + wave * 16 + quad * 4 + r;
        attn_o[row * (size_t)(H_ * VDIM_) + h * VDIM_ + nt * 16 + l15] =
            f2bf(o[nt][r] * invl[r]);
      }
  };

  STAGE(0, 0);  // prologue: tile 0 -> buf 0

  for (int it = 0; it < 33; ++it) {
    const int cur = it & 1;
    const int nxt = cur ^ 1;
    const bool ph1 = (it >= n0);
    const int qt = ph1 ? qtB : qtA;
    const int kt = ph1 ? (it - n0) : it;

    // WAR fence: all waves finished reading buf[nxt] (compute of it-1).
    __builtin_amdgcn_s_barrier();
    asm volatile("" ::: "memory");

    if (it + 1 < 33) {
      const bool p1n = (it + 1 >= n0);
      const int kt2 = p1n ? (it + 1 - n0) : (it + 1);
      STAGE(nxt, kt2);                              // prefetch tile it+1
      asm volatile("s_waitcnt vmcnt(10)" ::: "memory");  // my tile-it loads done
    } else {
      asm volatile("s_waitcnt vmcnt(0)" ::: "memory");
    }
    // RAW fence: ALL waves' tile-it loads landed in buf[cur].
    __builtin_amdgcn_s_barrier();
    asm volatile("" ::: "memory");
    __builtin_amdgcn_sched_barrier(0);

    // --- S = Q K^T (wave strip 16 x 64) ---
    f32x4 sacc[4];
#pragma unroll
    for (int nt = 0; nt < 4; ++nt) { f32x4 z = {0.f, 0.f, 0.f, 0.f}; sacc[nt] = z; }
#pragma unroll
    for (int s = 0; s < 4; ++s) {
#pragma unroll
      for (int nt = 0; nt < 4; ++nt) {
        const int key = nt * 16 + l15;
        short8 kb = *(const short8*)&Ksn[cur][(key * 16 + ((s * 4 + quad) ^ (key & 15))) * 8];
        sacc[nt] = __builtin_amdgcn_mfma_f32_16x16x32_bf16(qf[s], kb, sacc[nt], 0, 0, 0);
      }
    }
#pragma unroll
    for (int s = 4; s < 6; ++s) {
#pragma unroll
      for (int nt = 0; nt < 4; ++nt) {
        const int key = nt * 16 + l15;
        short8 kb = *(const short8*)&Ksr[cur][(key * 8 + (((s - 4) * 4 + quad) ^ (key & 7))) * 8];
        sacc[nt] = __builtin_amdgcn_mfma_f32_16x16x32_bf16(qf[s], kb, sacc[nt], 0, 0, 0);
      }
    }

    float sc[4][4];
#pragma unroll
    for (int nt = 0; nt < 4; ++nt)
#pragma unroll
      for (int r = 0; r < 4; ++r) {
        float v = sacc[nt][r] * scale2;
        if (kt == qt && (nt * 16 + l15) > (wave * 16 + quad * 4 + r)) v = -1e30f;
        sc[nt][r] = v;
      }

    float mt[4];
#pragma unroll
    for (int r = 0; r < 4; ++r)
      mt[r] = fmaxf(fmaxf(sc[0][r], sc[1][r]), fmaxf(sc[2][r], sc[3][r]));
#pragma unroll
    for (int mask = 1; mask <= 8; mask <<= 1)
#pragma unroll
      for (int r = 0; r < 4; ++r) mt[r] = fmaxf(mt[r], __shfl_xor(mt[r], mask, 64));

    float al[4], rs[4];
#pragma unroll
    for (int r = 0; r < 4; ++r) {
      const float mn = fmaxf(m_st[r], mt[r]);
      al[r] = exp2f(m_st[r] - mn);
      m_st[r] = mn;
      rs[r] = 0.f;
    }
#pragma unroll
    for (int nt = 0; nt < 4; ++nt)
#pragma unroll
      for (int r = 0; r < 4; ++r) {
        const float p = exp2f(sc[nt][r] - m_st[r]);
        sc[nt][r] = p;
        rs[r] += p;
      }
#pragma unroll
    for (int mask = 1; mask <= 8; mask <<= 1)
#pragma unroll
      for (int r = 0; r < 4; ++r) rs[r] += __shfl_xor(rs[r], mask, 64);
#pragma unroll
    for (int r = 0; r < 4; ++r) l_st[r] = l_st[r] * al[r] + rs[r];

    // --- P transpose via LDS (wave-private rows; no block barrier needed) ---
#pragma unroll
    for (int nt = 0; nt < 4; ++nt)
#pragma unroll
      for (int r = 0; r < 4; ++r)
        Ps[(wave * 16 + quad * 4 + r) * LV + nt * 16 + l15] = f2bf(sc[nt][r]);
    __builtin_amdgcn_wave_barrier();  // pin order; same-wave DS ops complete in order

    // --- O = O*alpha + P V ---
#pragma unroll
    for (int nt = 0; nt < 8; ++nt)
#pragma unroll
      for (int r = 0; r < 4; ++r) o[nt][r] *= al[r];
#pragma unroll
    for (int s = 0; s < 2; ++s) {
      short8 pa = *(const short8*)&Ps[(wave * 16 + l15) * LV + s * 32 + quad * 8];
#pragma unroll
      for (int nt = 0; nt < 8; ++nt) {
        const int f = nt * 16 + l15;
        short8 vb = *(const short8*)&Vt[cur][(f * 8 + ((s * 4 + quad) ^ (f & 7))) * 8];
        o[nt] = __builtin_amdgcn_mfma_f32_16x16x32_bf16(pa, vb, o[nt], 0, 0, 0);
      }
    }

    // Phase boundary: flush strip A, reload Q for strip B, reset state.
    // (Stores/loads here are older VMEM ops at the next counted wait ->
    // conservatively drained; uniform branch -> no barrier divergence.)
    if (it == n0 - 1) {
      EPI(qtA);
      LOADQ(qf, qtB);
#pragma unroll
      for (int r = 0; r < 4; ++r) { m_st[r] = -1e30f; l_st[r] = 0.f; }
#pragma unroll
      for (int nt = 0; nt < 8; ++nt) { f32x4 z = {0.f, 0.f, 0.f, 0.f}; o[nt] = z; }
    }
  }

  EPI(qtB);
}

// ---------------------------------------------------------------------------
// Launch
// ---------------------------------------------------------------------------
extern "C" void kernel_launch(void* const* d_in, const int* in_sizes, int n_in,
                              void* d_out, int out_size, void* d_ws, size_t ws_size,
                              hipStream_t stream) {
  (void)in_sizes; (void)n_in;
  const float* x         = (const float*)d_in[0];
  const float* wq_down   = (const float*)d_in[1];
  const float* q_norm_w  = (const float*)d_in[2];
  const float* wq_up     = (const float*)d_in[3];
  const float* wq_rope   = (const float*)d_in[4];
  const float* wkv_down  = (const float*)d_in[5];
  const float* kv_norm_w = (const float*)d_in[6];
  const float* wkv_up    = (const float*)d_in[7];
  const float* wk_rope   = (const float*)d_in[8];
  const float* wo        = (const float*)d_in[9];
  float* out = (float*)d_out;

  // ---- workspace carve (identical layout to the passing run)
  const size_t SZ_XBF   = (size_t)TOK_ * DIM_ * 2;
  const size_t SZ_WQD   = (size_t)QR_ * DIM_ * 2;
  const size_t SZ_WKVD  = (size_t)KVR_ * DIM_ * 2;
  const size_t SZ_WKR   = (size_t)ROPE_ * DIM_ * 2;
  const size_t SZ_WQU   = (size_t)H_ * NOPE_ * QR_ * 2;
  const size_t SZ_WQR   = (size_t)H_ * ROPE_ * QR_ * 2;
  const size_t SZ_WKVU  = (size_t)H_ * (NOPE_ + VDIM_) * KVR_ * 2;
  const size_t SZ_WO    = (size_t)DIM_ * H_ * VDIM_ * 2;
  const size_t SZ_QC    = (size_t)TOK_ * QR_ * 4;   // aliases: q_pe fp32, then vt_g
  const size_t SZ_KVC   = (size_t)TOK_ * KVR_ * 4;
  const size_t SZ_QCN   = (size_t)TOK_ * QR_ * 2;
  const size_t SZ_KVCN  = (size_t)TOK_ * KVR_ * 2;
  const size_t SZ_QNOPE = (size_t)TOK_ * H_ * NOPE_ * 2; // aliases attn_o bf16
  const size_t SZ_QPEB  = (size_t)TOK_ * H_ * ROPE_ * 2;
  const size_t SZ_KRF   = (size_t)TOK_ * ROPE_ * 4;
  const size_t SZ_KRB   = (size_t)TOK_ * ROPE_ * 2;
  const size_t SZ_KVUP  = (size_t)TOK_ * H_ * (NOPE_ + VDIM_) * 2;
  const size_t NEED = SZ_XBF + SZ_WQD + SZ_WKVD + SZ_WKR + SZ_WQU + SZ_WQR + SZ_WKVU +
                      SZ_WO + SZ_QC + SZ_KVC + SZ_QCN + SZ_KVCN + SZ_QNOPE + SZ_QPEB +
                      SZ_KRF + SZ_KRB + SZ_KVUP;
  if (ws_size < NEED) {
    hipMemsetAsync(d_out, 0, (size_t)out_size * sizeof(float), stream);
    return;
  }
  char* p = (char*)d_ws;
  unsigned short* x_bf    = (unsigned short*)p; p += SZ_XBF;
  unsigned short* wqd_bf  = (unsigned short*)p; p += SZ_WQD;
  unsigned short* wkvd_bf = (unsigned short*)p; p += SZ_WKVD;
  unsigned short* wkr_bf  = (unsigned short*)p; p += SZ_WKR;
  unsigned short* wqu_bf  = (unsigned short*)p; p += SZ_WQU;
  unsigned short* wqr_bf  = (unsigned short*)p; p += SZ_WQR;
  unsigned short* wkvu_bf = (unsigned short*)p; p += SZ_WKVU;
  unsigned short* wo_bf   = (unsigned short*)p; p += SZ_WO;
  float*          q_c     = (float*)p;          p += SZ_QC;
  float*          kv_c    = (float*)p;          p += SZ_KVC;
  unsigned short* q_cn    = (unsigned short*)p; p += SZ_QCN;
  unsigned short* kv_cn   = (unsigned short*)p; p += SZ_KVCN;
  unsigned short* q_nope  = (unsigned short*)p; p += SZ_QNOPE;
  unsigned short* q_pe_bf = (unsigned short*)p; p += SZ_QPEB;
  float*          k_ropef = (float*)p;          p += SZ_KRF;
  unsigned short* k_ropeb = (unsigned short*)p; p += SZ_KRB;
  unsigned short* kv_upbf = (unsigned short*)p; p += SZ_KVUP;
  float*          q_pe_f  = q_c;                   // q_c dead after rmsnorm
  unsigned short* vt_g    = (unsigned short*)q_c;  // q_pe_f dead after rope_q
  unsigned short* attn_o  = q_nope;                // q_nope dead after flash

  const dim3 blk(256);
  // ---- one-time bf16 casts
  cvt_bf16<<<(TOK_ * DIM_ / 8 + 255) / 256, blk, 0, stream>>>(x, x_bf, TOK_ * DIM_ / 8);
  cvt_bf16<<<(QR_ * DIM_ / 8 + 255) / 256, blk, 0, stream>>>(wq_down, wqd_bf, QR_ * DIM_ / 8);
  cvt_bf16<<<(KVR_ * DIM_ / 8 + 255) / 256, blk, 0, stream>>>(wkv_down, wkvd_bf, KVR_ * DIM_ / 8);
  cvt_bf16<<<(ROPE_ * DIM_ / 8 + 255) / 256, blk, 0, stream>>>(wk_rope, wkr_bf, ROPE_ * DIM_ / 8);
  cvt_bf16<<<(H_ * NOPE_ * QR_ / 8 + 255) / 256, blk, 0, stream>>>(wq_up, wqu_bf, H_ * NOPE_ * QR_ / 8);
  cvt_bf16<<<(H_ * ROPE_ * QR_ / 8 + 255) / 256, blk, 0, stream>>>(wq_rope, wqr_bf, H_ * ROPE_ * QR_ / 8);
  cvt_bf16<<<(H_ * (NOPE_ + VDIM_) * KVR_ / 8 + 255) / 256, blk, 0, stream>>>(wkv_up, wkvu_bf,
                                                                              H_ * (NOPE_ + VDIM_) * KVR_ / 8);
  cvt_bf16<<<(DIM_ * H_ * VDIM_ / 8 + 255) / 256, blk, 0, stream>>>(wo, wo_bf, DIM_ * H_ * VDIM_ / 8);

  // ---- down projections
  gemm_bf16<float, 4><<<dim3(QR_ / 128, TOK_ / 128), blk, 0, stream>>>(x_bf, wqd_bf, q_c, TOK_, QR_, DIM_);
  gemm_bf16<float, 2><<<dim3(KVR_ / 64, TOK_ / 128), blk, 0, stream>>>(x_bf, wkvd_bf, kv_c, TOK_, KVR_, DIM_);
  gemm_bf16<float, 2><<<dim3(1, TOK_ / 128), blk, 0, stream>>>(x_bf, wkr_bf, k_ropef, TOK_, ROPE_, DIM_);

  // ---- RMSNorms
  rmsnorm_bf16<<<TOK_, blk, 0, stream>>>(q_c, q_norm_w, q_cn, QR_);
  rmsnorm_bf16<<<TOK_, blk, 0, stream>>>(kv_c, kv_norm_w, kv_cn, KVR_);

  // ---- up projections
  gemm_bf16<unsigned short, 4><<<dim3(H_ * NOPE_ / 128, TOK_ / 128), blk, 0, stream>>>(
      q_cn, wqu_bf, q_nope, TOK_, H_ * NOPE_, QR_);
  gemm_bf16<float, 4><<<dim3(H_ * ROPE_ / 128, TOK_ / 128), blk, 0, stream>>>(
      q_cn, wqr_bf, q_pe_f, TOK_, H_ * ROPE_, QR_);
  gemm_bf16<unsigned short, 4><<<dim3(H_ * (NOPE_ + VDIM_) / 128, TOK_ / 128), blk, 0, stream>>>(
      kv_cn, wkvu_bf, kv_upbf, TOK_, H_ * (NOPE_ + VDIM_), KVR_);

  // ---- RoPE (q first: frees q_c region for vt_g)
  {
    const int pairs_q = TOK_ * H_ * 32;
    rope_bf16<<<(pairs_q + 255) / 256, blk, 0, stream>>>(q_pe_f, q_pe_bf, H_, pairs_q);
    const int pairs_k = TOK_ * 32;
    rope_bf16<<<(pairs_k + 255) / 256, blk, 0, stream>>>(k_ropef, k_ropeb, 1, pairs_k);
  }

  // ---- V transpose (after rope_q; vt_g aliases q_c region)
  transpose_v<<<dim3(S_ / 64, H_, B_), blk, 0, stream>>>(kv_upbf, vt_g);

  // ---- attention (balanced pairs, double-buffered pipeline: grid.x = 16)
  flash_attn_mfma<<<dim3(16, H_, B_), blk, 0, stream>>>(q_nope, q_pe_bf, kv_upbf, k_ropeb, vt_g, attn_o);

  // ---- output projection
  gemm_bf16<float, 4><<<dim3(DIM_ / 128, TOK_ / 128), blk, 0, stream>>>(attn_o, wo_bf, out, TOK_, DIM_, H_ * VDIM_);
}